// Round 11
// baseline (1372.372 us; speedup 1.0000x reference)
//
#include <hip/hip_runtime.h>

// PointNet++ SA module: FPS -> ball query -> group -> SharedMLP(3) -> maxpool
// B=8, N=8192, C_IN=64, M=1024, K=64, RADIUS=0.2, MLP=[64,64,128]

#define B_ 8
#define N_ 8192
#define M_ 1024
#define K_ 64
#define FTW 68  // 3 xyz + 64 feat + 1 pad (row = 272B, 16B aligned)

// ---------------------------------------------------------------------------
// u64-key lexicographic merge via DPP (VALU pipe, no LDS).
// key = (f32bits(val) << 32) | ~idx ; distances >= 0 so f32 bits order as u32.
// max(key) == (val desc, idx asc) — associative, any mixing schedule valid.
// ---------------------------------------------------------------------------
template <int CTRL>
__device__ __forceinline__ unsigned long long dpp_key(unsigned long long k) {
  int lo = __builtin_amdgcn_update_dpp(0, (int)(unsigned int)k, CTRL, 0xF, 0xF, true);
  int hi = __builtin_amdgcn_update_dpp(0, (int)(unsigned int)(k >> 32), CTRL, 0xF, 0xF, true);
  unsigned long long o = ((unsigned long long)(unsigned int)hi << 32) | (unsigned int)lo;
  return o > k ? o : k;
}

// 6-level DPP max (pure VALU). Valid global result in lane 63.
// Safe for values >= 0 (bcast zero-fill merges 0.f).
template <int CTRL>
__device__ __forceinline__ float dpp_fmax(float v) {
  int o = __builtin_amdgcn_update_dpp(0, __float_as_int(v), CTRL, 0xF, 0xF, true);
  return fmaxf(v, __int_as_float(o));
}
__device__ __forceinline__ float wave_fmax63(float v) {
  v = dpp_fmax<0xB1>(v);   // quad_perm xor1
  v = dpp_fmax<0x4E>(v);   // quad_perm xor2
  v = dpp_fmax<0x141>(v);  // row_half_mirror
  v = dpp_fmax<0x140>(v);  // row_mirror -> row max in all 16 lanes
  v = dpp_fmax<0x142>(v);  // row_bcast15
  v = dpp_fmax<0x143>(v);  // row_bcast31 -> lane 63 = wave max
  return v;
}

// ---------------------------------------------------------------------------
// Kernel 1 (fused): blocks 0..7 = exact FPS (one CU per batch);
//                   blocks 8..  = build ft[b][n][0..67] = {x,y,z,f0..f63,0}.
// FPS: 256 threads (4 waves, 1/SIMD) x 32 points — R4/R8 schedule, the
// measured best (890us) of the family {512x8:2515, 512x16-R3:1265, this:890,
// value-first:1058, pk:1005, 512x16-R10:927}. ONE barrier per iteration,
// parity double-buffered candidates; index carried in the u64 key so the
// post-barrier combine is per-thread self-contained.
// Arithmetic identical to reference: unfused f32 sub/mul/add in x,y,z order;
// argmax tie-break = first occurrence (lexicographic val desc, idx asc).
// ---------------------------------------------------------------------------
__global__ __launch_bounds__(256, 1) void fps_ft_kernel(const float* __restrict__ xyz,
                                                        const float* __restrict__ feat,
                                                        float* __restrict__ ft,
                                                        float* __restrict__ nxyz) {
#pragma clang fp contract(off)
  if (blockIdx.x >= 8) {
    // ---- build_ft path (no LDS use, no barriers) ----
    const int nb = gridDim.x - 8;
    const int total = B_ * N_ * FTW;
    for (int idx = (blockIdx.x - 8) * 256 + threadIdx.x; idx < total; idx += nb * 256) {
      int c = idx % FTW;
      int bn = idx / FTW;
      int n = bn & (N_ - 1);
      int b = bn >> 13;
      float v;
      if (c < 3) v = xyz[(b * 3 + c) * N_ + n];
      else if (c < 67) v = feat[(b * 64 + (c - 3)) * N_ + n];
      else v = 0.f;
      ft[idx] = v;
    }
    return;
  }

  // ---- FPS path ----
  __shared__ float4 pts4[N_];                    // 128 KB point table (w unused)
  __shared__ unsigned long long cand[2][16];     // parity-buffered row-winner keys
  __shared__ int scidx[M_];
  const int b = blockIdx.x;
  const int t = threadIdx.x;
  const int lane = t & 63;
  const int wid = t >> 6;  // 0..3
  const float* xb = xyz + b * 3 * N_;

  for (int n = t; n < N_; n += 256) {
    pts4[n] = make_float4(xb[n], xb[N_ + n], xb[2 * N_ + n], 0.f);
  }

  const int base = t * 32;
  float px[32], py[32], pz[32], mind[32];
#pragma unroll
  for (int j = 0; j < 32; ++j) {
    px[j] = xb[base + j];
    py[j] = xb[N_ + base + j];
    pz[j] = xb[2 * N_ + base + j];
    mind[j] = 1e10f;
  }
  float xl = xb[0], yl = xb[N_], zl = xb[2 * N_];
  if (t == 0) scidx[0] = 0;
  __syncthreads();

  for (int i = 1; i < M_; ++i) {
    float bestv = -1.f;
    int bl = 0;  // local index 0..31 (inline-const cndmask)
#pragma unroll
    for (int j = 0; j < 32; ++j) {
      float dx = __fsub_rn(px[j], xl);
      float dy = __fsub_rn(py[j], yl);
      float dz = __fsub_rn(pz[j], zl);
      float d = __fadd_rn(__fadd_rn(__fmul_rn(dx, dx), __fmul_rn(dy, dy)), __fmul_rn(dz, dz));
      float md = fminf(mind[j], d);
      mind[j] = md;
      if (md > bestv) { bestv = md; bl = j; }  // ascending j -> first max kept
    }
    unsigned long long key =
        ((unsigned long long)__float_as_uint(bestv) << 32) | (unsigned int)(~(base + bl));
    // in-wave reduce to 16-lane-row winners: 4 DPP levels, VALU pipe only
    key = dpp_key<0xB1>(key);   // quad_perm [1,0,3,2]
    key = dpp_key<0x4E>(key);   // quad_perm [2,3,0,1]
    key = dpp_key<0x141>(key);  // row_half_mirror
    key = dpp_key<0x140>(key);  // row_mirror -> 16-lane-row winner
    if ((lane & 15) == 0) cand[i & 1][wid * 4 + (lane >> 4)] = key;
    __syncthreads();
    // combine 16 row winners: broadcast read, 4 DPP levels within each 16-row
    unsigned long long gk = cand[i & 1][lane & 15];
    gk = dpp_key<0xB1>(gk);
    gk = dpp_key<0x4E>(gk);
    gk = dpp_key<0x141>(gk);
    gk = dpp_key<0x140>(gk);
    const int gi = (int)(~(unsigned int)gk);
    if (t == 0) scidx[i] = gi;
    float4 cc = pts4[gi];  // broadcast ds_read_b128, conflict-free
    xl = cc.x; yl = cc.y; zl = cc.z;
    // no second barrier: next iteration's leader writes go to the other parity
  }
  __syncthreads();
  for (int q = t; q < M_; q += 256) {
    int ci = scidx[q];
    float4 c = pts4[ci];
    nxyz[b * 3 * M_ + q] = c.x;
    nxyz[b * 3 * M_ + M_ + q] = c.y;
    nxyz[b * 3 * M_ + 2 * M_ + q] = c.z;
  }
}

// ---------------------------------------------------------------------------
// Kernel 2 (fused): ball query + group + SharedMLP(67->64->64->128) + max.
// One wave (64 threads) per centroid (b,m).
// Phase A (ballq, verbatim logic from the standalone kernel): ordered first-K
//   within radius via ballot/prefix-popcount; expanded-form distance exactly
//   as reference (unfused f32); 0.04f threshold; pad with first hit. Indices
//   land in a 64-int LDS scratch (no global nidx round-trip).
// Phase B (mlp): lane = neighbor column; 4-way output unroll; 64x33 LDS
//   half-bridge (two 32-output phases, stride 33 = conflict-free);
//   DPP wave-max pooling (pure VALU) + readlane. FMA order == reference.
// __launch_bounds__(64,5): VGPR cap keeps 4 waves/SIMD; LDS 8.7KB no bind.
// ---------------------------------------------------------------------------
template <bool USE_FT>
__global__ __launch_bounds__(64, 5) void ballq_mlp_kernel(
    const float* __restrict__ ft, const float* __restrict__ xyz, const float* __restrict__ feat,
    const float* __restrict__ nxyz,
    const float* __restrict__ w0, const float* __restrict__ s0, const float* __restrict__ b0,
    const float* __restrict__ w1, const float* __restrict__ s1, const float* __restrict__ b1,
    const float* __restrict__ w2, const float* __restrict__ s2, const float* __restrict__ b2,
    float* __restrict__ out2) {
  __shared__ float ylds[64 * 33];  // 8448 B half-bridge
  __shared__ int islot[K_];        // per-wave neighbor indices (256 B)
  const int g = blockIdx.x;
  const int b = g >> 10;
  const int m = g & (M_ - 1);
  const int lane = threadIdx.x;
  const float* xb = xyz + b * 3 * N_;
  const float cx = nxyz[b * 3 * M_ + m];
  const float cy = nxyz[b * 3 * M_ + M_ + m];
  const float cz = nxyz[b * 3 * M_ + 2 * M_ + m];

  // ---- Phase A: ball query (exact reference semantics) ----
  {
    const float nc = __fadd_rn(__fadd_rn(__fmul_rn(cx, cx), __fmul_rn(cy, cy)), __fmul_rn(cz, cz));
    int cnt = 0;
    int first = 0;
    for (int basei = 0; basei < N_ && cnt < K_; basei += 64) {
      const int n = basei + lane;
      float p_x = xb[n], p_y = xb[N_ + n], p_z = xb[2 * N_ + n];
      float pn = __fadd_rn(__fadd_rn(__fmul_rn(p_x, p_x), __fmul_rn(p_y, p_y)), __fmul_rn(p_z, p_z));
      float dt = __fadd_rn(__fadd_rn(__fmul_rn(cx, p_x), __fmul_rn(cy, p_y)), __fmul_rn(cz, p_z));
      float d2 = __fsub_rn(__fadd_rn(nc, pn), __fmul_rn(2.f, dt));
      bool inr = d2 < 0.04f;
      unsigned long long mk = __ballot(inr);
      if (cnt == 0 && mk != 0ull) first = basei + (__ffsll((long long)mk) - 1);
      int pos = cnt + (int)__popcll(mk & ((1ull << lane) - 1ull));
      if (inr && pos < K_) islot[pos] = n;
      cnt += (int)__popcll(mk);
    }
    if (cnt > K_) cnt = K_;
    if (lane >= cnt) islot[lane] = first;  // pad with first hit (0 if none)
  }
  __syncthreads();  // single wave: orders the LDS scatter before the read
  const int n = islot[lane];

  // ---- Phase B: group + MLP + maxpool ----
  float x0[67];
  if (USE_FT) {
    const float4* row = (const float4*)(ft + (size_t)((b << 13) + n) * FTW);
    float f[FTW];
#pragma unroll
    for (int q = 0; q < 17; ++q) {
      float4 v = row[q];
      f[q * 4 + 0] = v.x; f[q * 4 + 1] = v.y; f[q * 4 + 2] = v.z; f[q * 4 + 3] = v.w;
    }
    x0[0] = f[0] - cx; x0[1] = f[1] - cy; x0[2] = f[2] - cz;
#pragma unroll
    for (int c = 3; c < 67; ++c) x0[c] = f[c];
  } else {
    x0[0] = xb[n] - cx; x0[1] = xb[N_ + n] - cy; x0[2] = xb[2 * N_ + n] - cz;
#pragma unroll
    for (int c = 0; c < 64; ++c) x0[3 + c] = feat[((b << 6) + c) * N_ + n];
  }

  float x1[64];
  // Layer 0: 67 -> 64 in two 32-output phases through the half-bridge
#pragma unroll
  for (int h = 0; h < 2; ++h) {
    for (int oo = 0; oo < 32; oo += 4) {
      const int o = h * 32 + oo;
      const float* wr = w0 + o * 67;
      float a0 = 0.f, a1 = 0.f, a2 = 0.f, a3 = 0.f;
#pragma unroll
      for (int ci = 0; ci < 67; ++ci) {
        float xvv = x0[ci];
        a0 = fmaf(wr[ci], xvv, a0);
        a1 = fmaf(wr[67 + ci], xvv, a1);
        a2 = fmaf(wr[134 + ci], xvv, a2);
        a3 = fmaf(wr[201 + ci], xvv, a3);
      }
      ylds[lane * 33 + oo + 0] = fmaxf(fmaf(a0, s0[o + 0], b0[o + 0]), 0.f);
      ylds[lane * 33 + oo + 1] = fmaxf(fmaf(a1, s0[o + 1], b0[o + 1]), 0.f);
      ylds[lane * 33 + oo + 2] = fmaxf(fmaf(a2, s0[o + 2], b0[o + 2]), 0.f);
      ylds[lane * 33 + oo + 3] = fmaxf(fmaf(a3, s0[o + 3], b0[o + 3]), 0.f);
    }
#pragma unroll
    for (int c = 0; c < 32; ++c) x1[h * 32 + c] = ylds[lane * 33 + c];
  }

  float x2[64];
  // Layer 1: 64 -> 64 in two 32-output phases
#pragma unroll
  for (int h = 0; h < 2; ++h) {
    for (int oo = 0; oo < 32; oo += 4) {
      const int o = h * 32 + oo;
      const float* wr = w1 + o * 64;
      float a0 = 0.f, a1 = 0.f, a2 = 0.f, a3 = 0.f;
#pragma unroll
      for (int ci = 0; ci < 64; ++ci) {
        float xvv = x1[ci];
        a0 = fmaf(wr[ci], xvv, a0);
        a1 = fmaf(wr[64 + ci], xvv, a1);
        a2 = fmaf(wr[128 + ci], xvv, a2);
        a3 = fmaf(wr[192 + ci], xvv, a3);
      }
      ylds[lane * 33 + oo + 0] = fmaxf(fmaf(a0, s1[o + 0], b1[o + 0]), 0.f);
      ylds[lane * 33 + oo + 1] = fmaxf(fmaf(a1, s1[o + 1], b1[o + 1]), 0.f);
      ylds[lane * 33 + oo + 2] = fmaxf(fmaf(a2, s1[o + 2], b1[o + 2]), 0.f);
      ylds[lane * 33 + oo + 3] = fmaxf(fmaf(a3, s1[o + 3], b1[o + 3]), 0.f);
    }
#pragma unroll
    for (int c = 0; c < 32; ++c) x2[h * 32 + c] = ylds[lane * 33 + c];
  }

  // Layer 2: 64 -> 128, fused max over K (4 outputs in flight, DPP reduce)
  float* outbm = out2 + (size_t)(b * 128) * M_ + m;
  for (int o = 0; o < 128; o += 4) {
    const float* wr = w2 + o * 64;
    float a0 = 0.f, a1 = 0.f, a2 = 0.f, a3 = 0.f;
#pragma unroll
    for (int ci = 0; ci < 64; ++ci) {
      float xvv = x2[ci];
      a0 = fmaf(wr[ci], xvv, a0);
      a1 = fmaf(wr[64 + ci], xvv, a1);
      a2 = fmaf(wr[128 + ci], xvv, a2);
      a3 = fmaf(wr[192 + ci], xvv, a3);
    }
    float v0 = fmaxf(fmaf(a0, s2[o + 0], b2[o + 0]), 0.f);
    float v1 = fmaxf(fmaf(a1, s2[o + 1], b2[o + 1]), 0.f);
    float v2 = fmaxf(fmaf(a2, s2[o + 2], b2[o + 2]), 0.f);
    float v3 = fmaxf(fmaf(a3, s2[o + 3], b2[o + 3]), 0.f);
    v0 = wave_fmax63(v0);
    v1 = wave_fmax63(v1);
    v2 = wave_fmax63(v2);
    v3 = wave_fmax63(v3);
    float g0 = __int_as_float(__builtin_amdgcn_readlane(__float_as_int(v0), 63));
    float g1 = __int_as_float(__builtin_amdgcn_readlane(__float_as_int(v1), 63));
    float g2 = __int_as_float(__builtin_amdgcn_readlane(__float_as_int(v2), 63));
    float g3 = __int_as_float(__builtin_amdgcn_readlane(__float_as_int(v3), 63));
    if (lane == ((o + 0) & 63)) outbm[(o + 0) * M_] = g0;
    if (lane == ((o + 1) & 63)) outbm[(o + 1) * M_] = g1;
    if (lane == ((o + 2) & 63)) outbm[(o + 2) * M_] = g2;
    if (lane == ((o + 3) & 63)) outbm[(o + 3) * M_] = g3;
  }
}

// ---------------------------------------------------------------------------
extern "C" void kernel_launch(void* const* d_in, const int* in_sizes, int n_in,
                              void* d_out, int out_size, void* d_ws, size_t ws_size,
                              hipStream_t stream) {
  const float* xyz = (const float*)d_in[0];
  const float* feat = (const float*)d_in[1];
  const float* w0 = (const float*)d_in[2];
  const float* s0 = (const float*)d_in[3];
  const float* b0 = (const float*)d_in[4];
  const float* w1 = (const float*)d_in[5];
  const float* s1 = (const float*)d_in[6];
  const float* b1 = (const float*)d_in[7];
  const float* w2 = (const float*)d_in[8];
  const float* s2 = (const float*)d_in[9];
  const float* b2 = (const float*)d_in[10];

  float* nxyz = (float*)d_out;                    // [8,3,1024]
  float* out2 = (float*)d_out + B_ * 3 * M_;      // [8,128,1024]

  const size_t ft_bytes = (size_t)B_ * N_ * FTW * sizeof(float);  // ~17.8 MB
  float* ft = (float*)d_ws;
  const bool use_ft = ws_size >= ft_bytes;

  // FPS (blocks 0-7) fused with ft-table build (blocks 8-63) — independent work.
  hipLaunchKernelGGL(fps_ft_kernel, dim3(use_ft ? 64 : 8), dim3(256), 0, stream,
                     xyz, feat, ft, nxyz);
  if (use_ft) {
    hipLaunchKernelGGL((ballq_mlp_kernel<true>), dim3(B_ * M_), dim3(64), 0, stream,
                       ft, xyz, feat, nxyz, w0, s0, b0, w1, s1, b1, w2, s2, b2, out2);
  } else {
    hipLaunchKernelGGL((ballq_mlp_kernel<false>), dim3(B_ * M_), dim3(64), 0, stream,
                       ft, xyz, feat, nxyz, w0, s0, b0, w1, s1, b1, w2, s2, b2, out2);
  }
}

// Round 12
// 1282.173 us; speedup vs baseline: 1.0703x; 1.0703x over previous
//
#include <hip/hip_runtime.h>

// PointNet++ SA module: FPS -> ball query -> group -> SharedMLP(3) -> maxpool
// B=8, N=8192, C_IN=64, M=1024, K=64, RADIUS=0.2, MLP=[64,64,128]

#define B_ 8
#define N_ 8192
#define M_ 1024
#define K_ 64
#define FTW 68  // 3 xyz + 64 feat + 1 pad (row = 272B, 16B aligned)

// ---------------------------------------------------------------------------
// u64-key lexicographic merge via DPP (VALU pipe, no LDS).
// key = (f32bits(val) << 32) | ~idx ; distances >= 0 so f32 bits order as u32.
// max(key) == (val desc, idx asc) — associative, any mixing schedule valid.
// ---------------------------------------------------------------------------
template <int CTRL>
__device__ __forceinline__ unsigned long long dpp_key(unsigned long long k) {
  int lo = __builtin_amdgcn_update_dpp(0, (int)(unsigned int)k, CTRL, 0xF, 0xF, true);
  int hi = __builtin_amdgcn_update_dpp(0, (int)(unsigned int)(k >> 32), CTRL, 0xF, 0xF, true);
  unsigned long long o = ((unsigned long long)(unsigned int)hi << 32) | (unsigned int)lo;
  return o > k ? o : k;
}

// 6-level DPP max (pure VALU). Valid global result in lane 63.
// Safe for values >= 0 (bcast zero-fill merges 0.f).
template <int CTRL>
__device__ __forceinline__ float dpp_fmax(float v) {
  int o = __builtin_amdgcn_update_dpp(0, __float_as_int(v), CTRL, 0xF, 0xF, true);
  return fmaxf(v, __int_as_float(o));
}
__device__ __forceinline__ float wave_fmax63(float v) {
  v = dpp_fmax<0xB1>(v);   // quad_perm xor1
  v = dpp_fmax<0x4E>(v);   // quad_perm xor2
  v = dpp_fmax<0x141>(v);  // row_half_mirror
  v = dpp_fmax<0x140>(v);  // row_mirror -> row max in all 16 lanes
  v = dpp_fmax<0x142>(v);  // row_bcast15
  v = dpp_fmax<0x143>(v);  // row_bcast31 -> lane 63 = wave max
  return v;
}

// ---------------------------------------------------------------------------
// Kernel 1 (fused): blocks 0..7 = exact FPS (one CU per batch);
//                   blocks 8..  = build ft[b][n][0..67] = {x,y,z,f0..f63,0}.
// FPS: 256 threads (4 waves, 1/SIMD) x 32 points — R4/R8 schedule, the
// measured best (890us). ONE barrier per iteration, parity double-buffered
// candidates; index carried in the u64 key so the post-barrier combine is
// per-thread self-contained.
// Arithmetic identical to reference: unfused f32 sub/mul/add in x,y,z order;
// argmax tie-break = first occurrence (lexicographic val desc, idx asc).
// ---------------------------------------------------------------------------
__global__ __launch_bounds__(256, 1) void fps_ft_kernel(const float* __restrict__ xyz,
                                                        const float* __restrict__ feat,
                                                        float* __restrict__ ft,
                                                        float* __restrict__ nxyz) {
#pragma clang fp contract(off)
  if (blockIdx.x >= 8) {
    // ---- build_ft path (no LDS use, no barriers) ----
    const int nb = gridDim.x - 8;
    const int total = B_ * N_ * FTW;
    for (int idx = (blockIdx.x - 8) * 256 + threadIdx.x; idx < total; idx += nb * 256) {
      int c = idx % FTW;
      int bn = idx / FTW;
      int n = bn & (N_ - 1);
      int b = bn >> 13;
      float v;
      if (c < 3) v = xyz[(b * 3 + c) * N_ + n];
      else if (c < 67) v = feat[(b * 64 + (c - 3)) * N_ + n];
      else v = 0.f;
      ft[idx] = v;
    }
    return;
  }

  // ---- FPS path ----
  __shared__ float4 pts4[N_];                    // 128 KB point table (w unused)
  __shared__ unsigned long long cand[2][16];     // parity-buffered row-winner keys
  __shared__ int scidx[M_];
  const int b = blockIdx.x;
  const int t = threadIdx.x;
  const int lane = t & 63;
  const int wid = t >> 6;  // 0..3
  const float* xb = xyz + b * 3 * N_;

  for (int n = t; n < N_; n += 256) {
    pts4[n] = make_float4(xb[n], xb[N_ + n], xb[2 * N_ + n], 0.f);
  }

  const int base = t * 32;
  float px[32], py[32], pz[32], mind[32];
#pragma unroll
  for (int j = 0; j < 32; ++j) {
    px[j] = xb[base + j];
    py[j] = xb[N_ + base + j];
    pz[j] = xb[2 * N_ + base + j];
    mind[j] = 1e10f;
  }
  float xl = xb[0], yl = xb[N_], zl = xb[2 * N_];
  if (t == 0) scidx[0] = 0;
  __syncthreads();

  for (int i = 1; i < M_; ++i) {
    float bestv = -1.f;
    int bl = 0;  // local index 0..31 (inline-const cndmask)
#pragma unroll
    for (int j = 0; j < 32; ++j) {
      float dx = __fsub_rn(px[j], xl);
      float dy = __fsub_rn(py[j], yl);
      float dz = __fsub_rn(pz[j], zl);
      float d = __fadd_rn(__fadd_rn(__fmul_rn(dx, dx), __fmul_rn(dy, dy)), __fmul_rn(dz, dz));
      float md = fminf(mind[j], d);
      mind[j] = md;
      if (md > bestv) { bestv = md; bl = j; }  // ascending j -> first max kept
    }
    unsigned long long key =
        ((unsigned long long)__float_as_uint(bestv) << 32) | (unsigned int)(~(base + bl));
    // in-wave reduce to 16-lane-row winners: 4 DPP levels, VALU pipe only
    key = dpp_key<0xB1>(key);   // quad_perm [1,0,3,2]
    key = dpp_key<0x4E>(key);   // quad_perm [2,3,0,1]
    key = dpp_key<0x141>(key);  // row_half_mirror
    key = dpp_key<0x140>(key);  // row_mirror -> 16-lane-row winner
    if ((lane & 15) == 0) cand[i & 1][wid * 4 + (lane >> 4)] = key;
    __syncthreads();
    // combine 16 row winners: broadcast read, 4 DPP levels within each 16-row
    unsigned long long gk = cand[i & 1][lane & 15];
    gk = dpp_key<0xB1>(gk);
    gk = dpp_key<0x4E>(gk);
    gk = dpp_key<0x141>(gk);
    gk = dpp_key<0x140>(gk);
    const int gi = (int)(~(unsigned int)gk);
    if (t == 0) scidx[i] = gi;
    float4 cc = pts4[gi];  // broadcast ds_read_b128, conflict-free
    xl = cc.x; yl = cc.y; zl = cc.z;
    // no second barrier: next iteration's leader writes go to the other parity
  }
  __syncthreads();
  for (int q = t; q < M_; q += 256) {
    int ci = scidx[q];
    float4 c = pts4[ci];
    nxyz[b * 3 * M_ + q] = c.x;
    nxyz[b * 3 * M_ + M_ + q] = c.y;
    nxyz[b * 3 * M_ + 2 * M_ + q] = c.z;
  }
}

// ---------------------------------------------------------------------------
// Kernel 2: ball query — one wave per centroid, ordered first-K within radius.
// (Standalone: R11 showed fusing it into the MLP kernel costs ~70us.)
// Replicates the reference's expanded-form distance exactly (unfused f32).
// Threshold 0.04f == f32(0.2*0.2 computed in python f64).
// ---------------------------------------------------------------------------
__global__ __launch_bounds__(256) void ballq_kernel(const float* __restrict__ xyz,
                                                    const float* __restrict__ nxyz,
                                                    int* __restrict__ nidx) {
  const int lane = threadIdx.x & 63;
  const int g = blockIdx.x * 4 + (threadIdx.x >> 6);  // 0..8191 centroid id
  const int b = g >> 10;
  const int m = g & (M_ - 1);
  const float* xb = xyz + b * 3 * N_;
  const float cx = nxyz[b * 3 * M_ + m];
  const float cy = nxyz[b * 3 * M_ + M_ + m];
  const float cz = nxyz[b * 3 * M_ + 2 * M_ + m];
  const float nc = __fadd_rn(__fadd_rn(__fmul_rn(cx, cx), __fmul_rn(cy, cy)), __fmul_rn(cz, cz));
  int cnt = 0;
  int first = 0;
  int* slot = nidx + (g << 6);
  for (int basei = 0; basei < N_ && cnt < K_; basei += 64) {
    const int n = basei + lane;
    float p_x = xb[n], p_y = xb[N_ + n], p_z = xb[2 * N_ + n];
    float pn = __fadd_rn(__fadd_rn(__fmul_rn(p_x, p_x), __fmul_rn(p_y, p_y)), __fmul_rn(p_z, p_z));
    float dt = __fadd_rn(__fadd_rn(__fmul_rn(cx, p_x), __fmul_rn(cy, p_y)), __fmul_rn(cz, p_z));
    float d2 = __fsub_rn(__fadd_rn(nc, pn), __fmul_rn(2.f, dt));
    bool inr = d2 < 0.04f;
    unsigned long long mk = __ballot(inr);
    if (cnt == 0 && mk != 0ull) first = basei + (__ffsll((long long)mk) - 1);
    int pos = cnt + (int)__popcll(mk & ((1ull << lane) - 1ull));
    if (inr && pos < K_) slot[pos] = n;
    cnt += (int)__popcll(mk);
  }
  if (cnt > K_) cnt = K_;
  if (lane >= cnt) slot[lane] = first;  // pad with first hit (0 if none)
}

// ---------------------------------------------------------------------------
// Kernel 3: fused group + SharedMLP(67->64->64->128) + max over K.
// One wave per (b,m); lane = neighbor column. 4-way output unroll.
// R12 changes vs R8:
//   - __launch_bounds__(64,4): 128-VGPR cap. The (64,5)=102 cap was BELOW the
//     natural live set (~115-120 at end of layer 0) -> scratch spill in the
//     hot loop. 128 fits; residency 4 waves/SIMD (16 waves/CU, LDS allows 18).
//   - #pragma unroll 2 on the o-group loops: lets the compiler issue group
//     i+1's weight s_loads under group i's fmac chain (hides ~200cy L2
//     latency per group instead of exposing it).
// 64x33 LDS half-bridge (two 32-output phases, stride 33 conflict-free);
// DPP wave-max pooling + readlane. FMA order identical to reference.
// ---------------------------------------------------------------------------
template <bool USE_FT>
__global__ __launch_bounds__(64, 4) void mlp_kernel(
    const float* __restrict__ ft, const float* __restrict__ xyz, const float* __restrict__ feat,
    const int* __restrict__ nidx, const float* __restrict__ nxyz,
    const float* __restrict__ w0, const float* __restrict__ s0, const float* __restrict__ b0,
    const float* __restrict__ w1, const float* __restrict__ s1, const float* __restrict__ b1,
    const float* __restrict__ w2, const float* __restrict__ s2, const float* __restrict__ b2,
    float* __restrict__ out2) {
  __shared__ float ylds[64 * 33];  // 8448 B: half-bridge, two 32-out phases
  const int g = blockIdx.x;
  const int b = g >> 10;
  const int m = g & (M_ - 1);
  const int lane = threadIdx.x;
  const int n = nidx[(g << 6) + lane];
  const float cx = nxyz[b * 3 * M_ + m];
  const float cy = nxyz[b * 3 * M_ + M_ + m];
  const float cz = nxyz[b * 3 * M_ + 2 * M_ + m];

  float x0[67];
  if (USE_FT) {
    const float4* row = (const float4*)(ft + (size_t)((b << 13) + n) * FTW);
    float f[FTW];
#pragma unroll
    for (int q = 0; q < 17; ++q) {
      float4 v = row[q];
      f[q * 4 + 0] = v.x; f[q * 4 + 1] = v.y; f[q * 4 + 2] = v.z; f[q * 4 + 3] = v.w;
    }
    x0[0] = f[0] - cx; x0[1] = f[1] - cy; x0[2] = f[2] - cz;
#pragma unroll
    for (int c = 3; c < 67; ++c) x0[c] = f[c];
  } else {
    const float* xb = xyz + b * 3 * N_;
    x0[0] = xb[n] - cx; x0[1] = xb[N_ + n] - cy; x0[2] = xb[2 * N_ + n] - cz;
#pragma unroll
    for (int c = 0; c < 64; ++c) x0[3 + c] = feat[((b << 6) + c) * N_ + n];
  }

  float x1[64];
  // Layer 0: 67 -> 64 in two 32-output phases through the half-bridge
#pragma unroll
  for (int h = 0; h < 2; ++h) {
#pragma unroll 2
    for (int oo = 0; oo < 32; oo += 4) {
      const int o = h * 32 + oo;
      const float* wr = w0 + o * 67;
      float a0 = 0.f, a1 = 0.f, a2 = 0.f, a3 = 0.f;
#pragma unroll
      for (int ci = 0; ci < 67; ++ci) {
        float xvv = x0[ci];
        a0 = fmaf(wr[ci], xvv, a0);
        a1 = fmaf(wr[67 + ci], xvv, a1);
        a2 = fmaf(wr[134 + ci], xvv, a2);
        a3 = fmaf(wr[201 + ci], xvv, a3);
      }
      ylds[lane * 33 + oo + 0] = fmaxf(fmaf(a0, s0[o + 0], b0[o + 0]), 0.f);
      ylds[lane * 33 + oo + 1] = fmaxf(fmaf(a1, s0[o + 1], b0[o + 1]), 0.f);
      ylds[lane * 33 + oo + 2] = fmaxf(fmaf(a2, s0[o + 2], b0[o + 2]), 0.f);
      ylds[lane * 33 + oo + 3] = fmaxf(fmaf(a3, s0[o + 3], b0[o + 3]), 0.f);
    }
#pragma unroll
    for (int c = 0; c < 32; ++c) x1[h * 32 + c] = ylds[lane * 33 + c];
  }

  float x2[64];
  // Layer 1: 64 -> 64 in two 32-output phases
#pragma unroll
  for (int h = 0; h < 2; ++h) {
#pragma unroll 2
    for (int oo = 0; oo < 32; oo += 4) {
      const int o = h * 32 + oo;
      const float* wr = w1 + o * 64;
      float a0 = 0.f, a1 = 0.f, a2 = 0.f, a3 = 0.f;
#pragma unroll
      for (int ci = 0; ci < 64; ++ci) {
        float xvv = x1[ci];
        a0 = fmaf(wr[ci], xvv, a0);
        a1 = fmaf(wr[64 + ci], xvv, a1);
        a2 = fmaf(wr[128 + ci], xvv, a2);
        a3 = fmaf(wr[192 + ci], xvv, a3);
      }
      ylds[lane * 33 + oo + 0] = fmaxf(fmaf(a0, s1[o + 0], b1[o + 0]), 0.f);
      ylds[lane * 33 + oo + 1] = fmaxf(fmaf(a1, s1[o + 1], b1[o + 1]), 0.f);
      ylds[lane * 33 + oo + 2] = fmaxf(fmaf(a2, s1[o + 2], b1[o + 2]), 0.f);
      ylds[lane * 33 + oo + 3] = fmaxf(fmaf(a3, s1[o + 3], b1[o + 3]), 0.f);
    }
#pragma unroll
    for (int c = 0; c < 32; ++c) x2[h * 32 + c] = ylds[lane * 33 + c];
  }

  // Layer 2: 64 -> 128, fused max over K (4 outputs in flight, DPP reduce)
  float* outbm = out2 + (size_t)(b * 128) * M_ + m;
#pragma unroll 2
  for (int o = 0; o < 128; o += 4) {
    const float* wr = w2 + o * 64;
    float a0 = 0.f, a1 = 0.f, a2 = 0.f, a3 = 0.f;
#pragma unroll
    for (int ci = 0; ci < 64; ++ci) {
      float xvv = x2[ci];
      a0 = fmaf(wr[ci], xvv, a0);
      a1 = fmaf(wr[64 + ci], xvv, a1);
      a2 = fmaf(wr[128 + ci], xvv, a2);
      a3 = fmaf(wr[192 + ci], xvv, a3);
    }
    float v0 = fmaxf(fmaf(a0, s2[o + 0], b2[o + 0]), 0.f);
    float v1 = fmaxf(fmaf(a1, s2[o + 1], b2[o + 1]), 0.f);
    float v2 = fmaxf(fmaf(a2, s2[o + 2], b2[o + 2]), 0.f);
    float v3 = fmaxf(fmaf(a3, s2[o + 3], b2[o + 3]), 0.f);
    v0 = wave_fmax63(v0);
    v1 = wave_fmax63(v1);
    v2 = wave_fmax63(v2);
    v3 = wave_fmax63(v3);
    float g0 = __int_as_float(__builtin_amdgcn_readlane(__float_as_int(v0), 63));
    float g1 = __int_as_float(__builtin_amdgcn_readlane(__float_as_int(v1), 63));
    float g2 = __int_as_float(__builtin_amdgcn_readlane(__float_as_int(v2), 63));
    float g3 = __int_as_float(__builtin_amdgcn_readlane(__float_as_int(v3), 63));
    if (lane == ((o + 0) & 63)) outbm[(o + 0) * M_] = g0;
    if (lane == ((o + 1) & 63)) outbm[(o + 1) * M_] = g1;
    if (lane == ((o + 2) & 63)) outbm[(o + 2) * M_] = g2;
    if (lane == ((o + 3) & 63)) outbm[(o + 3) * M_] = g3;
  }
}

// ---------------------------------------------------------------------------
extern "C" void kernel_launch(void* const* d_in, const int* in_sizes, int n_in,
                              void* d_out, int out_size, void* d_ws, size_t ws_size,
                              hipStream_t stream) {
  const float* xyz = (const float*)d_in[0];
  const float* feat = (const float*)d_in[1];
  const float* w0 = (const float*)d_in[2];
  const float* s0 = (const float*)d_in[3];
  const float* b0 = (const float*)d_in[4];
  const float* w1 = (const float*)d_in[5];
  const float* s1 = (const float*)d_in[6];
  const float* b1 = (const float*)d_in[7];
  const float* w2 = (const float*)d_in[8];
  const float* s2 = (const float*)d_in[9];
  const float* b2 = (const float*)d_in[10];

  float* nxyz = (float*)d_out;                    // [8,3,1024]
  float* out2 = (float*)d_out + B_ * 3 * M_;      // [8,128,1024]

  const size_t nidx_bytes = (size_t)B_ * M_ * K_ * sizeof(int);        // 2 MB
  const size_t ft_bytes = (size_t)B_ * N_ * FTW * sizeof(float);       // ~17.8 MB
  int* nidx = (int*)d_ws;
  float* ft = (float*)((char*)d_ws + nidx_bytes);
  const bool use_ft = ws_size >= nidx_bytes + ft_bytes;

  // FPS (blocks 0-7) fused with ft-table build (blocks 8-63) — independent work.
  hipLaunchKernelGGL(fps_ft_kernel, dim3(use_ft ? 64 : 8), dim3(256), 0, stream,
                     xyz, feat, ft, nxyz);
  hipLaunchKernelGGL(ballq_kernel, dim3(B_ * M_ / 4), dim3(256), 0, stream, xyz, nxyz, nidx);
  if (use_ft) {
    hipLaunchKernelGGL((mlp_kernel<true>), dim3(B_ * M_), dim3(64), 0, stream,
                       ft, xyz, feat, nidx, nxyz, w0, s0, b0, w1, s1, b1, w2, s2, b2, out2);
  } else {
    hipLaunchKernelGGL((mlp_kernel<false>), dim3(B_ * M_), dim3(64), 0, stream,
                       ft, xyz, feat, nidx, nxyz, w0, s0, b0, w1, s1, b1, w2, s2, b2, out2);
  }
}

// Round 13
// 1252.896 us; speedup vs baseline: 1.0954x; 1.0234x over previous
//
#include <hip/hip_runtime.h>

// PointNet++ SA module: FPS -> ball query -> group -> SharedMLP(3) -> maxpool
// B=8, N=8192, C_IN=64, M=1024, K=64, RADIUS=0.2, MLP=[64,64,128]

#define B_ 8
#define N_ 8192
#define M_ 1024
#define K_ 64
#define FTW 68  // 3 xyz + 64 feat + 1 pad (row = 272B, 16B aligned)

// ---------------------------------------------------------------------------
// u64-key lexicographic merge via DPP (VALU pipe, no LDS).
// key = (f32bits(val) << 32) | ~idx ; distances >= 0 so f32 bits order as u32.
// max(key) == (val desc, idx asc) — associative, any mixing schedule valid.
// ---------------------------------------------------------------------------
template <int CTRL>
__device__ __forceinline__ unsigned long long dpp_key(unsigned long long k) {
  int lo = __builtin_amdgcn_update_dpp(0, (int)(unsigned int)k, CTRL, 0xF, 0xF, true);
  int hi = __builtin_amdgcn_update_dpp(0, (int)(unsigned int)(k >> 32), CTRL, 0xF, 0xF, true);
  unsigned long long o = ((unsigned long long)(unsigned int)hi << 32) | (unsigned int)lo;
  return o > k ? o : k;
}

// 6-level DPP max (pure VALU), used by the fallback mlp path.
template <int CTRL>
__device__ __forceinline__ float dpp_fmax(float v) {
  int o = __builtin_amdgcn_update_dpp(0, __float_as_int(v), CTRL, 0xF, 0xF, true);
  return fmaxf(v, __int_as_float(o));
}
__device__ __forceinline__ float wave_fmax63(float v) {
  v = dpp_fmax<0xB1>(v);
  v = dpp_fmax<0x4E>(v);
  v = dpp_fmax<0x141>(v);
  v = dpp_fmax<0x140>(v);
  v = dpp_fmax<0x142>(v);
  v = dpp_fmax<0x143>(v);
  return v;
}

// ---------------------------------------------------------------------------
// Kernel 1 (fused): blocks 0..7 = exact FPS (one CU per batch);
//                   blocks 8..  = build ft table + padded w0 (stride 68).
// FPS: 256 threads (4 waves, 1/SIMD) x 32 points — R4/R8 schedule, measured
// best (890us). ONE barrier per iteration, parity double-buffered candidates.
// Arithmetic identical to reference: unfused f32 sub/mul/add in x,y,z order;
// argmax tie-break = first occurrence (lexicographic val desc, idx asc).
// ---------------------------------------------------------------------------
__global__ __launch_bounds__(256, 1) void fps_ft_kernel(const float* __restrict__ xyz,
                                                        const float* __restrict__ feat,
                                                        const float* __restrict__ w0,
                                                        float* __restrict__ w0pad,
                                                        float* __restrict__ ft,
                                                        float* __restrict__ nxyz) {
#pragma clang fp contract(off)
  if (blockIdx.x >= 8) {
    // ---- builder path (no LDS use, no barriers) ----
    if (blockIdx.x == 8) {
      // padded w0: [64][68], cols 67 = 0 (16B-aligned rows for float4 loads)
      for (int i = threadIdx.x; i < 64 * FTW; i += 256) {
        int o = i / FTW, c = i % FTW;
        w0pad[i] = (c < 67) ? w0[o * 67 + c] : 0.f;
      }
    }
    const int nb = gridDim.x - 8;
    const int total = B_ * N_ * FTW;
    for (int idx = (blockIdx.x - 8) * 256 + threadIdx.x; idx < total; idx += nb * 256) {
      int c = idx % FTW;
      int bn = idx / FTW;
      int n = bn & (N_ - 1);
      int b = bn >> 13;
      float v;
      if (c < 3) v = xyz[(b * 3 + c) * N_ + n];
      else if (c < 67) v = feat[(b * 64 + (c - 3)) * N_ + n];
      else v = 0.f;
      ft[idx] = v;
    }
    return;
  }

  // ---- FPS path ----
  __shared__ float4 pts4[N_];                    // 128 KB point table (w unused)
  __shared__ unsigned long long cand[2][16];     // parity-buffered row-winner keys
  __shared__ int scidx[M_];
  const int b = blockIdx.x;
  const int t = threadIdx.x;
  const int lane = t & 63;
  const int wid = t >> 6;  // 0..3
  const float* xb = xyz + b * 3 * N_;

  for (int n = t; n < N_; n += 256) {
    pts4[n] = make_float4(xb[n], xb[N_ + n], xb[2 * N_ + n], 0.f);
  }

  const int base = t * 32;
  float px[32], py[32], pz[32], mind[32];
#pragma unroll
  for (int j = 0; j < 32; ++j) {
    px[j] = xb[base + j];
    py[j] = xb[N_ + base + j];
    pz[j] = xb[2 * N_ + base + j];
    mind[j] = 1e10f;
  }
  float xl = xb[0], yl = xb[N_], zl = xb[2 * N_];
  if (t == 0) scidx[0] = 0;
  __syncthreads();

  for (int i = 1; i < M_; ++i) {
    float bestv = -1.f;
    int bl = 0;  // local index 0..31 (inline-const cndmask)
#pragma unroll
    for (int j = 0; j < 32; ++j) {
      float dx = __fsub_rn(px[j], xl);
      float dy = __fsub_rn(py[j], yl);
      float dz = __fsub_rn(pz[j], zl);
      float d = __fadd_rn(__fadd_rn(__fmul_rn(dx, dx), __fmul_rn(dy, dy)), __fmul_rn(dz, dz));
      float md = fminf(mind[j], d);
      mind[j] = md;
      if (md > bestv) { bestv = md; bl = j; }  // ascending j -> first max kept
    }
    unsigned long long key =
        ((unsigned long long)__float_as_uint(bestv) << 32) | (unsigned int)(~(base + bl));
    key = dpp_key<0xB1>(key);
    key = dpp_key<0x4E>(key);
    key = dpp_key<0x141>(key);
    key = dpp_key<0x140>(key);  // -> 16-lane-row winner
    if ((lane & 15) == 0) cand[i & 1][wid * 4 + (lane >> 4)] = key;
    __syncthreads();
    unsigned long long gk = cand[i & 1][lane & 15];
    gk = dpp_key<0xB1>(gk);
    gk = dpp_key<0x4E>(gk);
    gk = dpp_key<0x141>(gk);
    gk = dpp_key<0x140>(gk);
    const int gi = (int)(~(unsigned int)gk);
    if (t == 0) scidx[i] = gi;
    float4 cc = pts4[gi];  // broadcast ds_read_b128, conflict-free
    xl = cc.x; yl = cc.y; zl = cc.z;
  }
  __syncthreads();
  for (int q = t; q < M_; q += 256) {
    int ci = scidx[q];
    float4 c = pts4[ci];
    nxyz[b * 3 * M_ + q] = c.x;
    nxyz[b * 3 * M_ + M_ + q] = c.y;
    nxyz[b * 3 * M_ + 2 * M_ + q] = c.z;
  }
}

// ---------------------------------------------------------------------------
// Kernel 2: ball query — one wave per centroid, ordered first-K within radius.
// Replicates the reference's expanded-form distance exactly (unfused f32).
// ---------------------------------------------------------------------------
__global__ __launch_bounds__(256) void ballq_kernel(const float* __restrict__ xyz,
                                                    const float* __restrict__ nxyz,
                                                    int* __restrict__ nidx) {
  const int lane = threadIdx.x & 63;
  const int g = blockIdx.x * 4 + (threadIdx.x >> 6);  // 0..8191 centroid id
  const int b = g >> 10;
  const int m = g & (M_ - 1);
  const float* xb = xyz + b * 3 * N_;
  const float cx = nxyz[b * 3 * M_ + m];
  const float cy = nxyz[b * 3 * M_ + M_ + m];
  const float cz = nxyz[b * 3 * M_ + 2 * M_ + m];
  const float nc = __fadd_rn(__fadd_rn(__fmul_rn(cx, cx), __fmul_rn(cy, cy)), __fmul_rn(cz, cz));
  int cnt = 0;
  int first = 0;
  int* slot = nidx + (g << 6);
  for (int basei = 0; basei < N_ && cnt < K_; basei += 64) {
    const int n = basei + lane;
    float p_x = xb[n], p_y = xb[N_ + n], p_z = xb[2 * N_ + n];
    float pn = __fadd_rn(__fadd_rn(__fmul_rn(p_x, p_x), __fmul_rn(p_y, p_y)), __fmul_rn(p_z, p_z));
    float dt = __fadd_rn(__fadd_rn(__fmul_rn(cx, p_x), __fmul_rn(cy, p_y)), __fmul_rn(cz, p_z));
    float d2 = __fsub_rn(__fadd_rn(nc, pn), __fmul_rn(2.f, dt));
    bool inr = d2 < 0.04f;
    unsigned long long mk = __ballot(inr);
    if (cnt == 0 && mk != 0ull) first = basei + (__ffsll((long long)mk) - 1);
    int pos = cnt + (int)__popcll(mk & ((1ull << lane) - 1ull));
    if (inr && pos < K_) slot[pos] = n;
    cnt += (int)__popcll(mk);
  }
  if (cnt > K_) cnt = K_;
  if (lane >= cnt) slot[lane] = first;  // pad with first hit (0 if none)
}

// ---------------------------------------------------------------------------
// Kernel 3 (primary): TRANSPOSED fused group+MLP+maxpool. One wave per (b,m);
// lane = OUTPUT CHANNEL. Weights live in per-lane VGPRs (loaded once per task
// via pipelined vector loads — kills the per-o-group scalar-load stream that
// R12 showed dominates). Neighbor activations: lane=k stages its own ft row
// into a 64x68 LDS buffer (17 float4 loads + ds_write_b128); consumed as
// uniform broadcast ds_read_b128 (conflict-free). Rows overwritten in place
// by each layer (read row k, write [k][lane] same iteration — in-order DS,
// single wave, no barriers). Layer 2 keeps both 64-reg weight halves (2
// independent FMA chains) and folds maxpool into a running per-lane fmaxf.
// FMA count & order per output identical to reference (ci ascending; the
// padded 68th term is 0*0 -> exact). absmax stays 0.
// ---------------------------------------------------------------------------
__global__ __launch_bounds__(64, 3) void mlp_t_kernel(
    const float* __restrict__ ft, const float* __restrict__ w0pad,
    const int* __restrict__ nidx, const float* __restrict__ nxyz,
    const float* __restrict__ s0, const float* __restrict__ b0,
    const float* __restrict__ w1, const float* __restrict__ s1, const float* __restrict__ b1,
    const float* __restrict__ w2, const float* __restrict__ s2, const float* __restrict__ b2,
    float* __restrict__ out2) {
  __shared__ float xls[64 * FTW];  // 17408 B activation buffer, reused per layer
  const int g = blockIdx.x;
  const int b = g >> 10;
  const int m = g & (M_ - 1);
  const int lane = threadIdx.x;

  const float cx = nxyz[b * 3 * M_ + m];
  const float cy = nxyz[b * 3 * M_ + M_ + m];
  const float cz = nxyz[b * 3 * M_ + 2 * M_ + m];

  // ---- stage: lane = neighbor k copies its ft row to LDS (recentered xyz) ----
  {
    const int nk = nidx[(g << 6) + lane];
    const float4* src = (const float4*)(ft + (size_t)((b << 13) + nk) * FTW);
    float4* dst = (float4*)(xls + lane * FTW);
    float4 v0 = src[0];
    v0.x -= cx; v0.y -= cy; v0.z -= cz;
    dst[0] = v0;
#pragma unroll
    for (int q = 1; q < 17; ++q) dst[q] = src[q];
  }
  // single wave: DS ops in order; compiler inserts the needed waitcnts.

  // ---- Layer 0: 67(+pad) -> 64 ; weights in 68 VGPRs ----
  float w0r[FTW];
  {
    const float4* wp = (const float4*)(w0pad + lane * FTW);
#pragma unroll
    for (int q = 0; q < 17; ++q) {
      float4 wv = wp[q];
      w0r[4 * q + 0] = wv.x; w0r[4 * q + 1] = wv.y;
      w0r[4 * q + 2] = wv.z; w0r[4 * q + 3] = wv.w;
    }
  }
  const float s0l = s0[lane], b0l = b0[lane];
  for (int k = 0; k < 64; k += 2) {
    const float4* rowA = (const float4*)(xls + k * FTW);
    const float4* rowB = (const float4*)(xls + (k + 1) * FTW);
    float aA = 0.f, aB = 0.f;
#pragma unroll
    for (int q = 0; q < 17; ++q) {
      float4 xa = rowA[q];
      float4 xbv = rowB[q];
      aA = fmaf(w0r[4 * q + 0], xa.x, aA);
      aA = fmaf(w0r[4 * q + 1], xa.y, aA);
      aA = fmaf(w0r[4 * q + 2], xa.z, aA);
      aA = fmaf(w0r[4 * q + 3], xa.w, aA);
      aB = fmaf(w0r[4 * q + 0], xbv.x, aB);
      aB = fmaf(w0r[4 * q + 1], xbv.y, aB);
      aB = fmaf(w0r[4 * q + 2], xbv.z, aB);
      aB = fmaf(w0r[4 * q + 3], xbv.w, aB);
    }
    xls[k * FTW + lane] = fmaxf(fmaf(aA, s0l, b0l), 0.f);
    xls[(k + 1) * FTW + lane] = fmaxf(fmaf(aB, s0l, b0l), 0.f);
  }

  // ---- Layer 1: 64 -> 64 ; weights in 64 VGPRs ----
  float w1r[64];
  {
    const float4* wp = (const float4*)(w1 + lane * 64);
#pragma unroll
    for (int q = 0; q < 16; ++q) {
      float4 wv = wp[q];
      w1r[4 * q + 0] = wv.x; w1r[4 * q + 1] = wv.y;
      w1r[4 * q + 2] = wv.z; w1r[4 * q + 3] = wv.w;
    }
  }
  const float s1l = s1[lane], b1l = b1[lane];
  for (int k = 0; k < 64; k += 2) {
    const float4* rowA = (const float4*)(xls + k * FTW);
    const float4* rowB = (const float4*)(xls + (k + 1) * FTW);
    float aA = 0.f, aB = 0.f;
#pragma unroll
    for (int q = 0; q < 16; ++q) {
      float4 xa = rowA[q];
      float4 xbv = rowB[q];
      aA = fmaf(w1r[4 * q + 0], xa.x, aA);
      aA = fmaf(w1r[4 * q + 1], xa.y, aA);
      aA = fmaf(w1r[4 * q + 2], xa.z, aA);
      aA = fmaf(w1r[4 * q + 3], xa.w, aA);
      aB = fmaf(w1r[4 * q + 0], xbv.x, aB);
      aB = fmaf(w1r[4 * q + 1], xbv.y, aB);
      aB = fmaf(w1r[4 * q + 2], xbv.z, aB);
      aB = fmaf(w1r[4 * q + 3], xbv.w, aB);
    }
    xls[k * FTW + lane] = fmaxf(fmaf(aA, s1l, b1l), 0.f);
    xls[(k + 1) * FTW + lane] = fmaxf(fmaf(aB, s1l, b1l), 0.f);
  }

  // ---- Layer 2: 64 -> 128 with fused max over k; lane owns channels
  //      lane and lane+64 (both weight rows in VGPRs, 2 FMA chains) ----
  float w2a[64], w2b[64];
  {
    const float4* wpa = (const float4*)(w2 + lane * 64);
    const float4* wpb = (const float4*)(w2 + (64 + lane) * 64);
#pragma unroll
    for (int q = 0; q < 16; ++q) {
      float4 wv = wpa[q];
      w2a[4 * q + 0] = wv.x; w2a[4 * q + 1] = wv.y;
      w2a[4 * q + 2] = wv.z; w2a[4 * q + 3] = wv.w;
      float4 wu = wpb[q];
      w2b[4 * q + 0] = wu.x; w2b[4 * q + 1] = wu.y;
      w2b[4 * q + 2] = wu.z; w2b[4 * q + 3] = wu.w;
    }
  }
  const float s2a = s2[lane], b2a = b2[lane];
  const float s2b = s2[64 + lane], b2b = b2[64 + lane];
  float vmaxA = 0.f, vmaxB = 0.f;  // relu outputs are >= 0
  for (int k = 0; k < 64; ++k) {
    const float4* row = (const float4*)(xls + k * FTW);
    float aA = 0.f, aB = 0.f;
#pragma unroll
    for (int q = 0; q < 16; ++q) {
      float4 xa = row[q];
      aA = fmaf(w2a[4 * q + 0], xa.x, aA);
      aA = fmaf(w2a[4 * q + 1], xa.y, aA);
      aA = fmaf(w2a[4 * q + 2], xa.z, aA);
      aA = fmaf(w2a[4 * q + 3], xa.w, aA);
      aB = fmaf(w2b[4 * q + 0], xa.x, aB);
      aB = fmaf(w2b[4 * q + 1], xa.y, aB);
      aB = fmaf(w2b[4 * q + 2], xa.z, aB);
      aB = fmaf(w2b[4 * q + 3], xa.w, aB);
    }
    vmaxA = fmaxf(vmaxA, fmaxf(fmaf(aA, s2a, b2a), 0.f));
    vmaxB = fmaxf(vmaxB, fmaxf(fmaf(aB, s2b, b2b), 0.f));
  }
  out2[(size_t)((b << 7) + lane) * M_ + m] = vmaxA;
  out2[(size_t)((b << 7) + 64 + lane) * M_ + m] = vmaxB;
}

// ---------------------------------------------------------------------------
// Kernel 3 (fallback, no-ws path): R12 mlp (lane = neighbor, scalar weights).
// ---------------------------------------------------------------------------
__global__ __launch_bounds__(64, 4) void mlp_kernel_fb(
    const float* __restrict__ xyz, const float* __restrict__ feat,
    const int* __restrict__ nidx, const float* __restrict__ nxyz,
    const float* __restrict__ w0, const float* __restrict__ s0, const float* __restrict__ b0,
    const float* __restrict__ w1, const float* __restrict__ s1, const float* __restrict__ b1,
    const float* __restrict__ w2, const float* __restrict__ s2, const float* __restrict__ b2,
    float* __restrict__ out2) {
  __shared__ float ylds[64 * 33];
  const int g = blockIdx.x;
  const int b = g >> 10;
  const int m = g & (M_ - 1);
  const int lane = threadIdx.x;
  const int n = nidx[(g << 6) + lane];
  const float cx = nxyz[b * 3 * M_ + m];
  const float cy = nxyz[b * 3 * M_ + M_ + m];
  const float cz = nxyz[b * 3 * M_ + 2 * M_ + m];

  float x0[67];
  const float* xb = xyz + b * 3 * N_;
  x0[0] = xb[n] - cx; x0[1] = xb[N_ + n] - cy; x0[2] = xb[2 * N_ + n] - cz;
#pragma unroll
  for (int c = 0; c < 64; ++c) x0[3 + c] = feat[((b << 6) + c) * N_ + n];

  float x1[64];
#pragma unroll
  for (int h = 0; h < 2; ++h) {
#pragma unroll 2
    for (int oo = 0; oo < 32; oo += 4) {
      const int o = h * 32 + oo;
      const float* wr = w0 + o * 67;
      float a0 = 0.f, a1 = 0.f, a2 = 0.f, a3 = 0.f;
#pragma unroll
      for (int ci = 0; ci < 67; ++ci) {
        float xvv = x0[ci];
        a0 = fmaf(wr[ci], xvv, a0);
        a1 = fmaf(wr[67 + ci], xvv, a1);
        a2 = fmaf(wr[134 + ci], xvv, a2);
        a3 = fmaf(wr[201 + ci], xvv, a3);
      }
      ylds[lane * 33 + oo + 0] = fmaxf(fmaf(a0, s0[o + 0], b0[o + 0]), 0.f);
      ylds[lane * 33 + oo + 1] = fmaxf(fmaf(a1, s0[o + 1], b0[o + 1]), 0.f);
      ylds[lane * 33 + oo + 2] = fmaxf(fmaf(a2, s0[o + 2], b0[o + 2]), 0.f);
      ylds[lane * 33 + oo + 3] = fmaxf(fmaf(a3, s0[o + 3], b0[o + 3]), 0.f);
    }
#pragma unroll
    for (int c = 0; c < 32; ++c) x1[h * 32 + c] = ylds[lane * 33 + c];
  }

  float x2[64];
#pragma unroll
  for (int h = 0; h < 2; ++h) {
#pragma unroll 2
    for (int oo = 0; oo < 32; oo += 4) {
      const int o = h * 32 + oo;
      const float* wr = w1 + o * 64;
      float a0 = 0.f, a1 = 0.f, a2 = 0.f, a3 = 0.f;
#pragma unroll
      for (int ci = 0; ci < 64; ++ci) {
        float xvv = x1[ci];
        a0 = fmaf(wr[ci], xvv, a0);
        a1 = fmaf(wr[64 + ci], xvv, a1);
        a2 = fmaf(wr[128 + ci], xvv, a2);
        a3 = fmaf(wr[192 + ci], xvv, a3);
      }
      ylds[lane * 33 + oo + 0] = fmaxf(fmaf(a0, s1[o + 0], b1[o + 0]), 0.f);
      ylds[lane * 33 + oo + 1] = fmaxf(fmaf(a1, s1[o + 1], b1[o + 1]), 0.f);
      ylds[lane * 33 + oo + 2] = fmaxf(fmaf(a2, s1[o + 2], b1[o + 2]), 0.f);
      ylds[lane * 33 + oo + 3] = fmaxf(fmaf(a3, s1[o + 3], b1[o + 3]), 0.f);
    }
#pragma unroll
    for (int c = 0; c < 32; ++c) x2[h * 32 + c] = ylds[lane * 33 + c];
  }

  float* outbm = out2 + (size_t)(b * 128) * M_ + m;
#pragma unroll 2
  for (int o = 0; o < 128; o += 4) {
    const float* wr = w2 + o * 64;
    float a0 = 0.f, a1 = 0.f, a2 = 0.f, a3 = 0.f;
#pragma unroll
    for (int ci = 0; ci < 64; ++ci) {
      float xvv = x2[ci];
      a0 = fmaf(wr[ci], xvv, a0);
      a1 = fmaf(wr[64 + ci], xvv, a1);
      a2 = fmaf(wr[128 + ci], xvv, a2);
      a3 = fmaf(wr[192 + ci], xvv, a3);
    }
    float v0 = fmaxf(fmaf(a0, s2[o + 0], b2[o + 0]), 0.f);
    float v1 = fmaxf(fmaf(a1, s2[o + 1], b2[o + 1]), 0.f);
    float v2 = fmaxf(fmaf(a2, s2[o + 2], b2[o + 2]), 0.f);
    float v3 = fmaxf(fmaf(a3, s2[o + 3], b2[o + 3]), 0.f);
    v0 = wave_fmax63(v0);
    v1 = wave_fmax63(v1);
    v2 = wave_fmax63(v2);
    v3 = wave_fmax63(v3);
    float g0 = __int_as_float(__builtin_amdgcn_readlane(__float_as_int(v0), 63));
    float g1 = __int_as_float(__builtin_amdgcn_readlane(__float_as_int(v1), 63));
    float g2 = __int_as_float(__builtin_amdgcn_readlane(__float_as_int(v2), 63));
    float g3 = __int_as_float(__builtin_amdgcn_readlane(__float_as_int(v3), 63));
    if (lane == ((o + 0) & 63)) outbm[(o + 0) * M_] = g0;
    if (lane == ((o + 1) & 63)) outbm[(o + 1) * M_] = g1;
    if (lane == ((o + 2) & 63)) outbm[(o + 2) * M_] = g2;
    if (lane == ((o + 3) & 63)) outbm[(o + 3) * M_] = g3;
  }
}

// ---------------------------------------------------------------------------
extern "C" void kernel_launch(void* const* d_in, const int* in_sizes, int n_in,
                              void* d_out, int out_size, void* d_ws, size_t ws_size,
                              hipStream_t stream) {
  const float* xyz = (const float*)d_in[0];
  const float* feat = (const float*)d_in[1];
  const float* w0 = (const float*)d_in[2];
  const float* s0 = (const float*)d_in[3];
  const float* b0 = (const float*)d_in[4];
  const float* w1 = (const float*)d_in[5];
  const float* s1 = (const float*)d_in[6];
  const float* b1 = (const float*)d_in[7];
  const float* w2 = (const float*)d_in[8];
  const float* s2 = (const float*)d_in[9];
  const float* b2 = (const float*)d_in[10];

  float* nxyz = (float*)d_out;                    // [8,3,1024]
  float* out2 = (float*)d_out + B_ * 3 * M_;      // [8,128,1024]

  // ws layout: nidx [2MB] | w0pad [17408B] | ft [~17.8MB]
  const size_t nidx_bytes = (size_t)B_ * M_ * K_ * sizeof(int);
  const size_t w0p_bytes = (size_t)64 * FTW * sizeof(float);
  const size_t ft_bytes = (size_t)B_ * N_ * FTW * sizeof(float);
  int* nidx = (int*)d_ws;
  float* w0pad = (float*)((char*)d_ws + nidx_bytes);
  float* ft = (float*)((char*)d_ws + nidx_bytes + w0p_bytes);
  const bool use_ft = ws_size >= nidx_bytes + w0p_bytes + ft_bytes;

  hipLaunchKernelGGL(fps_ft_kernel, dim3(use_ft ? 64 : 8), dim3(256), 0, stream,
                     xyz, feat, w0, w0pad, ft, nxyz);
  hipLaunchKernelGGL(ballq_kernel, dim3(B_ * M_ / 4), dim3(256), 0, stream, xyz, nxyz, nidx);
  if (use_ft) {
    hipLaunchKernelGGL(mlp_t_kernel, dim3(B_ * M_), dim3(64), 0, stream,
                       ft, w0pad, nidx, nxyz, s0, b0, w1, s1, b1, w2, s2, b2, out2);
  } else {
    hipLaunchKernelGGL(mlp_kernel_fb, dim3(B_ * M_), dim3(64), 0, stream,
                       xyz, feat, nidx, nxyz, w0, s0, b0, w1, s1, b1, w2, s2, b2, out2);
  }
}

// Round 14
// 1223.049 us; speedup vs baseline: 1.1221x; 1.0244x over previous
//
#include <hip/hip_runtime.h>

// PointNet++ SA module: FPS -> ball query -> group -> SharedMLP(3) -> maxpool
// B=8, N=8192, C_IN=64, M=1024, K=64, RADIUS=0.2, MLP=[64,64,128]

#define B_ 8
#define N_ 8192
#define M_ 1024
#define K_ 64
#define FTW 68  // 3 xyz + 64 feat + 1 pad (row = 272B, 16B aligned)

// ---------------------------------------------------------------------------
// u64-key lexicographic merge via DPP (VALU pipe, no LDS).
// key = (f32bits(val) << 32) | ~idx ; distances >= 0 so f32 bits order as u32.
// max(key) == (val desc, idx asc) — associative, any mixing schedule valid.
// ---------------------------------------------------------------------------
template <int CTRL>
__device__ __forceinline__ unsigned long long dpp_key(unsigned long long k) {
  int lo = __builtin_amdgcn_update_dpp(0, (int)(unsigned int)k, CTRL, 0xF, 0xF, true);
  int hi = __builtin_amdgcn_update_dpp(0, (int)(unsigned int)(k >> 32), CTRL, 0xF, 0xF, true);
  unsigned long long o = ((unsigned long long)(unsigned int)hi << 32) | (unsigned int)lo;
  return o > k ? o : k;
}

// 6-level DPP max (pure VALU), used by the fallback mlp path.
template <int CTRL>
__device__ __forceinline__ float dpp_fmax(float v) {
  int o = __builtin_amdgcn_update_dpp(0, __float_as_int(v), CTRL, 0xF, 0xF, true);
  return fmaxf(v, __int_as_float(o));
}
__device__ __forceinline__ float wave_fmax63(float v) {
  v = dpp_fmax<0xB1>(v);
  v = dpp_fmax<0x4E>(v);
  v = dpp_fmax<0x141>(v);
  v = dpp_fmax<0x140>(v);
  v = dpp_fmax<0x142>(v);
  v = dpp_fmax<0x143>(v);
  return v;
}

// ---------------------------------------------------------------------------
// Kernel 1 (fused): blocks 0..7 = exact FPS (one CU per batch);
//                   blocks 8..  = build ft table + padded w0 (stride 68).
// FPS: 256 threads (4 waves, 1/SIMD) x 32 points — R4/R8 schedule, measured
// best (890us). ONE barrier per iteration, parity double-buffered candidates.
// Arithmetic identical to reference: unfused f32 sub/mul/add in x,y,z order;
// argmax tie-break = first occurrence (lexicographic val desc, idx asc).
// ---------------------------------------------------------------------------
__global__ __launch_bounds__(256, 1) void fps_ft_kernel(const float* __restrict__ xyz,
                                                        const float* __restrict__ feat,
                                                        const float* __restrict__ w0,
                                                        float* __restrict__ w0pad,
                                                        float* __restrict__ ft,
                                                        float* __restrict__ nxyz) {
#pragma clang fp contract(off)
  if (blockIdx.x >= 8) {
    // ---- builder path (no LDS use, no barriers) ----
    if (blockIdx.x == 8) {
      // padded w0: [64][68], cols 67 = 0 (16B-aligned rows for float4 loads)
      for (int i = threadIdx.x; i < 64 * FTW; i += 256) {
        int o = i / FTW, c = i % FTW;
        w0pad[i] = (c < 67) ? w0[o * 67 + c] : 0.f;
      }
    }
    const int nb = gridDim.x - 8;
    const int total = B_ * N_ * FTW;
    for (int idx = (blockIdx.x - 8) * 256 + threadIdx.x; idx < total; idx += nb * 256) {
      int c = idx % FTW;
      int bn = idx / FTW;
      int n = bn & (N_ - 1);
      int b = bn >> 13;
      float v;
      if (c < 3) v = xyz[(b * 3 + c) * N_ + n];
      else if (c < 67) v = feat[(b * 64 + (c - 3)) * N_ + n];
      else v = 0.f;
      ft[idx] = v;
    }
    return;
  }

  // ---- FPS path ----
  __shared__ float4 pts4[N_];                    // 128 KB point table (w unused)
  __shared__ unsigned long long cand[2][16];     // parity-buffered row-winner keys
  __shared__ int scidx[M_];
  const int b = blockIdx.x;
  const int t = threadIdx.x;
  const int lane = t & 63;
  const int wid = t >> 6;  // 0..3
  const float* xb = xyz + b * 3 * N_;

  for (int n = t; n < N_; n += 256) {
    pts4[n] = make_float4(xb[n], xb[N_ + n], xb[2 * N_ + n], 0.f);
  }

  const int base = t * 32;
  float px[32], py[32], pz[32], mind[32];
#pragma unroll
  for (int j = 0; j < 32; ++j) {
    px[j] = xb[base + j];
    py[j] = xb[N_ + base + j];
    pz[j] = xb[2 * N_ + base + j];
    mind[j] = 1e10f;
  }
  float xl = xb[0], yl = xb[N_], zl = xb[2 * N_];
  if (t == 0) scidx[0] = 0;
  __syncthreads();

  for (int i = 1; i < M_; ++i) {
    float bestv = -1.f;
    int bl = 0;  // local index 0..31 (inline-const cndmask)
#pragma unroll
    for (int j = 0; j < 32; ++j) {
      float dx = __fsub_rn(px[j], xl);
      float dy = __fsub_rn(py[j], yl);
      float dz = __fsub_rn(pz[j], zl);
      float d = __fadd_rn(__fadd_rn(__fmul_rn(dx, dx), __fmul_rn(dy, dy)), __fmul_rn(dz, dz));
      float md = fminf(mind[j], d);
      mind[j] = md;
      if (md > bestv) { bestv = md; bl = j; }  // ascending j -> first max kept
    }
    unsigned long long key =
        ((unsigned long long)__float_as_uint(bestv) << 32) | (unsigned int)(~(base + bl));
    key = dpp_key<0xB1>(key);
    key = dpp_key<0x4E>(key);
    key = dpp_key<0x141>(key);
    key = dpp_key<0x140>(key);  // -> 16-lane-row winner
    if ((lane & 15) == 0) cand[i & 1][wid * 4 + (lane >> 4)] = key;
    __syncthreads();
    unsigned long long gk = cand[i & 1][lane & 15];
    gk = dpp_key<0xB1>(gk);
    gk = dpp_key<0x4E>(gk);
    gk = dpp_key<0x141>(gk);
    gk = dpp_key<0x140>(gk);
    const int gi = (int)(~(unsigned int)gk);
    if (t == 0) scidx[i] = gi;
    float4 cc = pts4[gi];  // broadcast ds_read_b128, conflict-free
    xl = cc.x; yl = cc.y; zl = cc.z;
  }
  __syncthreads();
  for (int q = t; q < M_; q += 256) {
    int ci = scidx[q];
    float4 c = pts4[ci];
    nxyz[b * 3 * M_ + q] = c.x;
    nxyz[b * 3 * M_ + M_ + q] = c.y;
    nxyz[b * 3 * M_ + 2 * M_ + q] = c.z;
  }
}

// ---------------------------------------------------------------------------
// Kernel 2: ball query — one wave per centroid, ordered first-K within radius.
// Replicates the reference's expanded-form distance exactly (unfused f32).
// ---------------------------------------------------------------------------
__global__ __launch_bounds__(256) void ballq_kernel(const float* __restrict__ xyz,
                                                    const float* __restrict__ nxyz,
                                                    int* __restrict__ nidx) {
  const int lane = threadIdx.x & 63;
  const int g = blockIdx.x * 4 + (threadIdx.x >> 6);  // 0..8191 centroid id
  const int b = g >> 10;
  const int m = g & (M_ - 1);
  const float* xb = xyz + b * 3 * N_;
  const float cx = nxyz[b * 3 * M_ + m];
  const float cy = nxyz[b * 3 * M_ + M_ + m];
  const float cz = nxyz[b * 3 * M_ + 2 * M_ + m];
  const float nc = __fadd_rn(__fadd_rn(__fmul_rn(cx, cx), __fmul_rn(cy, cy)), __fmul_rn(cz, cz));
  int cnt = 0;
  int first = 0;
  int* slot = nidx + (g << 6);
  for (int basei = 0; basei < N_ && cnt < K_; basei += 64) {
    const int n = basei + lane;
    float p_x = xb[n], p_y = xb[N_ + n], p_z = xb[2 * N_ + n];
    float pn = __fadd_rn(__fadd_rn(__fmul_rn(p_x, p_x), __fmul_rn(p_y, p_y)), __fmul_rn(p_z, p_z));
    float dt = __fadd_rn(__fadd_rn(__fmul_rn(cx, p_x), __fmul_rn(cy, p_y)), __fmul_rn(cz, p_z));
    float d2 = __fsub_rn(__fadd_rn(nc, pn), __fmul_rn(2.f, dt));
    bool inr = d2 < 0.04f;
    unsigned long long mk = __ballot(inr);
    if (cnt == 0 && mk != 0ull) first = basei + (__ffsll((long long)mk) - 1);
    int pos = cnt + (int)__popcll(mk & ((1ull << lane) - 1ull));
    if (inr && pos < K_) slot[pos] = n;
    cnt += (int)__popcll(mk);
  }
  if (cnt > K_) cnt = K_;
  if (lane >= cnt) slot[lane] = first;  // pad with first hit (0 if none)
}

// ---------------------------------------------------------------------------
// Kernel 3 (primary): TRANSPOSED fused group+MLP+maxpool, TWO waves per task.
// Block = 128 threads; lane = OUTPUT CHANNEL; wave w owns rows [32w, 32w+32).
// Key property: output row k of every layer depends ONLY on input row k, so
// the two waves run all three layers independently on disjoint row halves
// (no inter-layer barriers). Weights per-lane in VGPRs (vector loads, loaded
// once per layer). Activations in a 64x68 LDS buffer: staged by 128 threads
// (half-row each), consumed as uniform broadcast ds_read_b128, overwritten
// in place per layer (reads of rows k,k+1 precede the writes — in-order DS
// within the owning wave; rows are wave-disjoint). Layer 2 keeps both weight
// halves (128 VGPRs, 2 FMA chains) and folds maxpool into running fmaxf over
// the wave's 32 rows; final cross-wave max via 2x128 LDS + barrier (exact:
// max is associative, relu outputs >= 0).
// FMA count & order per output identical to reference (ci ascending; padded
// 68th term is 0*0 -> exact). absmax stays 0.
// ---------------------------------------------------------------------------
__global__ __launch_bounds__(128, 2) void mlp_t_kernel(
    const float* __restrict__ ft, const float* __restrict__ w0pad,
    const int* __restrict__ nidx, const float* __restrict__ nxyz,
    const float* __restrict__ s0, const float* __restrict__ b0,
    const float* __restrict__ w1, const float* __restrict__ s1, const float* __restrict__ b1,
    const float* __restrict__ w2, const float* __restrict__ s2, const float* __restrict__ b2,
    float* __restrict__ out2) {
  __shared__ float xls[64 * FTW];  // 17408 B activation buffer, reused per layer
  __shared__ float red[2][128];    // cross-wave max combine
  const int g = blockIdx.x;
  const int b = g >> 10;
  const int m = g & (M_ - 1);
  const int t = threadIdx.x;
  const int lane = t & 63;
  const int wid = t >> 6;  // 0..1
  const int r0 = wid * 32;

  const float cx = nxyz[b * 3 * M_ + m];
  const float cy = nxyz[b * 3 * M_ + M_ + m];
  const float cz = nxyz[b * 3 * M_ + 2 * M_ + m];

  // ---- stage: thread t copies half of row (t>>1) to LDS (recentered xyz) ----
  {
    const int row = t >> 1;
    const int half = t & 1;
    const int nk = nidx[(g << 6) + row];
    const float4* src = (const float4*)(ft + (size_t)((b << 13) + nk) * FTW);
    float4* dst = (float4*)(xls + row * FTW);
    if (half == 0) {
      float4 v0 = src[0];
      v0.x -= cx; v0.y -= cy; v0.z -= cz;
      dst[0] = v0;
#pragma unroll
      for (int q = 1; q < 8; ++q) dst[q] = src[q];
    } else {
#pragma unroll
      for (int q = 8; q < 17; ++q) dst[q] = src[q];
    }
  }
  __syncthreads();

  // ---- Layer 0: 67(+pad) -> 64 ; weights in 68 VGPRs ----
  float w0r[FTW];
  {
    const float4* wp = (const float4*)(w0pad + lane * FTW);
#pragma unroll
    for (int q = 0; q < 17; ++q) {
      float4 wv = wp[q];
      w0r[4 * q + 0] = wv.x; w0r[4 * q + 1] = wv.y;
      w0r[4 * q + 2] = wv.z; w0r[4 * q + 3] = wv.w;
    }
  }
  const float s0l = s0[lane], b0l = b0[lane];
  for (int kk = 0; kk < 32; kk += 2) {
    const int k = r0 + kk;
    const float4* rowA = (const float4*)(xls + k * FTW);
    const float4* rowB = (const float4*)(xls + (k + 1) * FTW);
    float aA = 0.f, aB = 0.f;
#pragma unroll
    for (int q = 0; q < 17; ++q) {
      float4 xa = rowA[q];
      float4 xbv = rowB[q];
      aA = fmaf(w0r[4 * q + 0], xa.x, aA);
      aA = fmaf(w0r[4 * q + 1], xa.y, aA);
      aA = fmaf(w0r[4 * q + 2], xa.z, aA);
      aA = fmaf(w0r[4 * q + 3], xa.w, aA);
      aB = fmaf(w0r[4 * q + 0], xbv.x, aB);
      aB = fmaf(w0r[4 * q + 1], xbv.y, aB);
      aB = fmaf(w0r[4 * q + 2], xbv.z, aB);
      aB = fmaf(w0r[4 * q + 3], xbv.w, aB);
    }
    xls[k * FTW + lane] = fmaxf(fmaf(aA, s0l, b0l), 0.f);
    xls[(k + 1) * FTW + lane] = fmaxf(fmaf(aB, s0l, b0l), 0.f);
  }

  // ---- Layer 1: 64 -> 64 ; weights in 64 VGPRs ----
  float w1r[64];
  {
    const float4* wp = (const float4*)(w1 + lane * 64);
#pragma unroll
    for (int q = 0; q < 16; ++q) {
      float4 wv = wp[q];
      w1r[4 * q + 0] = wv.x; w1r[4 * q + 1] = wv.y;
      w1r[4 * q + 2] = wv.z; w1r[4 * q + 3] = wv.w;
    }
  }
  const float s1l = s1[lane], b1l = b1[lane];
  for (int kk = 0; kk < 32; kk += 2) {
    const int k = r0 + kk;
    const float4* rowA = (const float4*)(xls + k * FTW);
    const float4* rowB = (const float4*)(xls + (k + 1) * FTW);
    float aA = 0.f, aB = 0.f;
#pragma unroll
    for (int q = 0; q < 16; ++q) {
      float4 xa = rowA[q];
      float4 xbv = rowB[q];
      aA = fmaf(w1r[4 * q + 0], xa.x, aA);
      aA = fmaf(w1r[4 * q + 1], xa.y, aA);
      aA = fmaf(w1r[4 * q + 2], xa.z, aA);
      aA = fmaf(w1r[4 * q + 3], xa.w, aA);
      aB = fmaf(w1r[4 * q + 0], xbv.x, aB);
      aB = fmaf(w1r[4 * q + 1], xbv.y, aB);
      aB = fmaf(w1r[4 * q + 2], xbv.z, aB);
      aB = fmaf(w1r[4 * q + 3], xbv.w, aB);
    }
    xls[k * FTW + lane] = fmaxf(fmaf(aA, s1l, b1l), 0.f);
    xls[(k + 1) * FTW + lane] = fmaxf(fmaf(aB, s1l, b1l), 0.f);
  }

  // ---- Layer 2: 64 -> 128 with fused max over the wave's 32 rows; lane
  //      owns channels lane and lane+64 (both weight rows in VGPRs) ----
  float w2a[64], w2b[64];
  {
    const float4* wpa = (const float4*)(w2 + lane * 64);
    const float4* wpb = (const float4*)(w2 + (64 + lane) * 64);
#pragma unroll
    for (int q = 0; q < 16; ++q) {
      float4 wv = wpa[q];
      w2a[4 * q + 0] = wv.x; w2a[4 * q + 1] = wv.y;
      w2a[4 * q + 2] = wv.z; w2a[4 * q + 3] = wv.w;
      float4 wu = wpb[q];
      w2b[4 * q + 0] = wu.x; w2b[4 * q + 1] = wu.y;
      w2b[4 * q + 2] = wu.z; w2b[4 * q + 3] = wu.w;
    }
  }
  const float s2a = s2[lane], b2a = b2[lane];
  const float s2b = s2[64 + lane], b2b = b2[64 + lane];
  float vmaxA = 0.f, vmaxB = 0.f;  // relu outputs are >= 0
  for (int kk = 0; kk < 32; ++kk) {
    const float4* row = (const float4*)(xls + (r0 + kk) * FTW);
    float aA = 0.f, aB = 0.f;
#pragma unroll
    for (int q = 0; q < 16; ++q) {
      float4 xa = row[q];
      aA = fmaf(w2a[4 * q + 0], xa.x, aA);
      aA = fmaf(w2a[4 * q + 1], xa.y, aA);
      aA = fmaf(w2a[4 * q + 2], xa.z, aA);
      aA = fmaf(w2a[4 * q + 3], xa.w, aA);
      aB = fmaf(w2b[4 * q + 0], xa.x, aB);
      aB = fmaf(w2b[4 * q + 1], xa.y, aB);
      aB = fmaf(w2b[4 * q + 2], xa.z, aB);
      aB = fmaf(w2b[4 * q + 3], xa.w, aB);
    }
    vmaxA = fmaxf(vmaxA, fmaxf(fmaf(aA, s2a, b2a), 0.f));
    vmaxB = fmaxf(vmaxB, fmaxf(fmaf(aB, s2b, b2b), 0.f));
  }
  red[wid][lane] = vmaxA;
  red[wid][64 + lane] = vmaxB;
  __syncthreads();
  if (t < 128) {
    float v = fmaxf(red[0][t], red[1][t]);
    out2[(size_t)((b << 7) + t) * M_ + m] = v;
  }
}

// ---------------------------------------------------------------------------
// Kernel 3 (fallback, no-ws path): R12 mlp (lane = neighbor, scalar weights).
// ---------------------------------------------------------------------------
__global__ __launch_bounds__(64, 4) void mlp_kernel_fb(
    const float* __restrict__ xyz, const float* __restrict__ feat,
    const int* __restrict__ nidx, const float* __restrict__ nxyz,
    const float* __restrict__ w0, const float* __restrict__ s0, const float* __restrict__ b0,
    const float* __restrict__ w1, const float* __restrict__ s1, const float* __restrict__ b1,
    const float* __restrict__ w2, const float* __restrict__ s2, const float* __restrict__ b2,
    float* __restrict__ out2) {
  __shared__ float ylds[64 * 33];
  const int g = blockIdx.x;
  const int b = g >> 10;
  const int m = g & (M_ - 1);
  const int lane = threadIdx.x;
  const int n = nidx[(g << 6) + lane];
  const float cx = nxyz[b * 3 * M_ + m];
  const float cy = nxyz[b * 3 * M_ + M_ + m];
  const float cz = nxyz[b * 3 * M_ + 2 * M_ + m];

  float x0[67];
  const float* xb = xyz + b * 3 * N_;
  x0[0] = xb[n] - cx; x0[1] = xb[N_ + n] - cy; x0[2] = xb[2 * N_ + n] - cz;
#pragma unroll
  for (int c = 0; c < 64; ++c) x0[3 + c] = feat[((b << 6) + c) * N_ + n];

  float x1[64];
#pragma unroll
  for (int h = 0; h < 2; ++h) {
#pragma unroll 2
    for (int oo = 0; oo < 32; oo += 4) {
      const int o = h * 32 + oo;
      const float* wr = w0 + o * 67;
      float a0 = 0.f, a1 = 0.f, a2 = 0.f, a3 = 0.f;
#pragma unroll
      for (int ci = 0; ci < 67; ++ci) {
        float xvv = x0[ci];
        a0 = fmaf(wr[ci], xvv, a0);
        a1 = fmaf(wr[67 + ci], xvv, a1);
        a2 = fmaf(wr[134 + ci], xvv, a2);
        a3 = fmaf(wr[201 + ci], xvv, a3);
      }
      ylds[lane * 33 + oo + 0] = fmaxf(fmaf(a0, s0[o + 0], b0[o + 0]), 0.f);
      ylds[lane * 33 + oo + 1] = fmaxf(fmaf(a1, s0[o + 1], b0[o + 1]), 0.f);
      ylds[lane * 33 + oo + 2] = fmaxf(fmaf(a2, s0[o + 2], b0[o + 2]), 0.f);
      ylds[lane * 33 + oo + 3] = fmaxf(fmaf(a3, s0[o + 3], b0[o + 3]), 0.f);
    }
#pragma unroll
    for (int c = 0; c < 32; ++c) x1[h * 32 + c] = ylds[lane * 33 + c];
  }

  float x2[64];
#pragma unroll
  for (int h = 0; h < 2; ++h) {
#pragma unroll 2
    for (int oo = 0; oo < 32; oo += 4) {
      const int o = h * 32 + oo;
      const float* wr = w1 + o * 64;
      float a0 = 0.f, a1 = 0.f, a2 = 0.f, a3 = 0.f;
#pragma unroll
      for (int ci = 0; ci < 64; ++ci) {
        float xvv = x1[ci];
        a0 = fmaf(wr[ci], xvv, a0);
        a1 = fmaf(wr[64 + ci], xvv, a1);
        a2 = fmaf(wr[128 + ci], xvv, a2);
        a3 = fmaf(wr[192 + ci], xvv, a3);
      }
      ylds[lane * 33 + oo + 0] = fmaxf(fmaf(a0, s1[o + 0], b1[o + 0]), 0.f);
      ylds[lane * 33 + oo + 1] = fmaxf(fmaf(a1, s1[o + 1], b1[o + 1]), 0.f);
      ylds[lane * 33 + oo + 2] = fmaxf(fmaf(a2, s1[o + 2], b1[o + 2]), 0.f);
      ylds[lane * 33 + oo + 3] = fmaxf(fmaf(a3, s1[o + 3], b1[o + 3]), 0.f);
    }
#pragma unroll
    for (int c = 0; c < 32; ++c) x2[h * 32 + c] = ylds[lane * 33 + c];
  }

  float* outbm = out2 + (size_t)(b * 128) * M_ + m;
#pragma unroll 2
  for (int o = 0; o < 128; o += 4) {
    const float* wr = w2 + o * 64;
    float a0 = 0.f, a1 = 0.f, a2 = 0.f, a3 = 0.f;
#pragma unroll
    for (int ci = 0; ci < 64; ++ci) {
      float xvv = x2[ci];
      a0 = fmaf(wr[ci], xvv, a0);
      a1 = fmaf(wr[64 + ci], xvv, a1);
      a2 = fmaf(wr[128 + ci], xvv, a2);
      a3 = fmaf(wr[192 + ci], xvv, a3);
    }
    float v0 = fmaxf(fmaf(a0, s2[o + 0], b2[o + 0]), 0.f);
    float v1 = fmaxf(fmaf(a1, s2[o + 1], b2[o + 1]), 0.f);
    float v2 = fmaxf(fmaf(a2, s2[o + 2], b2[o + 2]), 0.f);
    float v3 = fmaxf(fmaf(a3, s2[o + 3], b2[o + 3]), 0.f);
    v0 = wave_fmax63(v0);
    v1 = wave_fmax63(v1);
    v2 = wave_fmax63(v2);
    v3 = wave_fmax63(v3);
    float g0 = __int_as_float(__builtin_amdgcn_readlane(__float_as_int(v0), 63));
    float g1 = __int_as_float(__builtin_amdgcn_readlane(__float_as_int(v1), 63));
    float g2 = __int_as_float(__builtin_amdgcn_readlane(__float_as_int(v2), 63));
    float g3 = __int_as_float(__builtin_amdgcn_readlane(__float_as_int(v3), 63));
    if (lane == ((o + 0) & 63)) outbm[(o + 0) * M_] = g0;
    if (lane == ((o + 1) & 63)) outbm[(o + 1) * M_] = g1;
    if (lane == ((o + 2) & 63)) outbm[(o + 2) * M_] = g2;
    if (lane == ((o + 3) & 63)) outbm[(o + 3) * M_] = g3;
  }
}

// ---------------------------------------------------------------------------
extern "C" void kernel_launch(void* const* d_in, const int* in_sizes, int n_in,
                              void* d_out, int out_size, void* d_ws, size_t ws_size,
                              hipStream_t stream) {
  const float* xyz = (const float*)d_in[0];
  const float* feat = (const float*)d_in[1];
  const float* w0 = (const float*)d_in[2];
  const float* s0 = (const float*)d_in[3];
  const float* b0 = (const float*)d_in[4];
  const float* w1 = (const float*)d_in[5];
  const float* s1 = (const float*)d_in[6];
  const float* b1 = (const float*)d_in[7];
  const float* w2 = (const float*)d_in[8];
  const float* s2 = (const float*)d_in[9];
  const float* b2 = (const float*)d_in[10];

  float* nxyz = (float*)d_out;                    // [8,3,1024]
  float* out2 = (float*)d_out + B_ * 3 * M_;      // [8,128,1024]

  // ws layout: nidx [2MB] | w0pad [17408B] | ft [~17.8MB]
  const size_t nidx_bytes = (size_t)B_ * M_ * K_ * sizeof(int);
  const size_t w0p_bytes = (size_t)64 * FTW * sizeof(float);
  const size_t ft_bytes = (size_t)B_ * N_ * FTW * sizeof(float);
  int* nidx = (int*)d_ws;
  float* w0pad = (float*)((char*)d_ws + nidx_bytes);
  float* ft = (float*)((char*)d_ws + nidx_bytes + w0p_bytes);
  const bool use_ft = ws_size >= nidx_bytes + w0p_bytes + ft_bytes;

  hipLaunchKernelGGL(fps_ft_kernel, dim3(use_ft ? 64 : 8), dim3(256), 0, stream,
                     xyz, feat, w0, w0pad, ft, nxyz);
  hipLaunchKernelGGL(ballq_kernel, dim3(B_ * M_ / 4), dim3(256), 0, stream, xyz, nxyz, nidx);
  if (use_ft) {
    hipLaunchKernelGGL(mlp_t_kernel, dim3(B_ * M_), dim3(128), 0, stream,
                       ft, w0pad, nidx, nxyz, s0, b0, w1, s1, b1, w2, s2, b2, out2);
  } else {
    hipLaunchKernelGGL(mlp_kernel_fb, dim3(B_ * M_), dim3(64), 0, stream,
                       xyz, feat, nidx, nxyz, w0, s0, b0, w1, s1, b1, w2, s2, b2, out2);
  }
}